// Round 11
// baseline (81.404 us; speedup 1.0000x reference)
//
#include <hip/hip_runtime.h>

#define NPTS 4096
#define NBATCH 16
#define THREADS 256
#define QPB 128          // queries per block (4 waves x 32; 1 A-frag/wave)
#define TCH 1024         // targets per LDS chunk
#define NCH (NPTS / TCH) // 4 chunks
#define NTP (TCH / 64)   // 16 tile-pairs per chunk

typedef __attribute__((ext_vector_type(8))) short short8;
typedef __attribute__((ext_vector_type(16))) float float16v;

static __device__ __forceinline__ unsigned short f2bf(float f) {
  unsigned int u = __builtin_bit_cast(unsigned int, f);
  u = (u + 0x7FFFu + ((u >> 16) & 1u)) >> 16;  // RNE
  return (unsigned short)u;
}
static __device__ __forceinline__ float bf2f(unsigned short h) {
  unsigned int u = ((unsigned int)h) << 16;
  return __builtin_bit_cast(float, u);
}
// Swizzled ushort offset of half-record h of target j (32B flat records,
// 16B-block XOR keyed by j's 128B group): staging writes and B-frag reads
// each cover all 32 banks per 8-lane phase (bank-math verified by hand).
static __device__ __forceinline__ int toff(int j, int h) {
  return (j * 16 + h * 8) ^ (((j >> 2) & 7) << 3);
}

// Chamfer, fp32, B=16, N=M=4096, d=3, bf16-split 32x32x16 MFMA.
// d2 emitted directly by the MFMA (K=13/16 slots; verified absmax 0.0 R9/R10):
//   A (query): [uhx,uhx,ulx, uhy,uhy,uly, uhz,uhz,ulz, 1,1, p2h,p2l, 0*3]
//   B (target):[thx,tlx,thx, thy,tly,thy, thz,tlz,thz, t2h,t2l, 1,1, 0*3]
// with u=-2p: sum_k A[k]B[k] = |p|^2 - 2p.t + |t|^2 = d2.
// R11 change: two-deep software pipeline. R8(2w/SIMD) == R10(4w/SIMD) == ~36us
// vs ~10us pipe work => per-iteration serialization (lgkm wait + MFMA->VALU
// result hazard with adjacent producer/consumer), not throughput. Now each
// iteration issues mfma(curr-from-prev-read), reads next+1, consumes
// min3(prev-mfma): every dependence spans a full iteration (~70 cyc).
// Grid (32,16,2)=1024 blocks -> 4 blocks/CU, 4 waves/SIMD; ~114 live regs
// under the 128-reg waves_per_eu(4,4) budget.
__global__ __launch_bounds__(THREADS)
__attribute__((amdgpu_waves_per_eu(4, 4)))
void chamfer_mfma(const float* __restrict__ shape,
                  const float* __restrict__ tmpl,
                  float* __restrict__ out) {
  __shared__ unsigned short tgt[TCH * 16];  // 32 KB swizzled records
  __shared__ unsigned short qry[QPB * 16];  // 4 KB flat records
  __shared__ float redbuf[4];

  const int qc = blockIdx.x;
  const int b = blockIdx.y;
  const int dir = blockIdx.z;
  const float* Pb = (dir == 0 ? shape : tmpl) + (size_t)b * NPTS * 3;
  const float* Tb = (dir == 0 ? tmpl : shape) + (size_t)b * NPTS * 3;

  const int tid = threadIdx.x;
  const int lane = tid & 63;
  const int wave = tid >> 6;
  const int n = lane & 31;   // MFMA row/col
  const int kg = lane >> 5;  // K-group: k = kg*8 + j

  // ---- Stage 128 queries: u=-2p split + p2 split record ----
  if (tid < QPB) {
    const int qg = qc * QPB + tid;
    const float px = Pb[3 * qg + 0], py = Pb[3 * qg + 1], pz = Pb[3 * qg + 2];
    const float ux = -2.0f * px, uy = -2.0f * py, uz = -2.0f * pz;
    const float p2 = fmaf(px, px, fmaf(py, py, pz * pz));
    const unsigned short hx = f2bf(ux), hy = f2bf(uy), hz = f2bf(uz);
    const unsigned short lx = f2bf(ux - bf2f(hx)), ly = f2bf(uy - bf2f(hy)),
                         lz = f2bf(uz - bf2f(hz));
    const unsigned short h2 = f2bf(p2), l2 = f2bf(p2 - bf2f(h2));
    const unsigned short ONE = 0x3F80;
    short8 v0, v1;
    v0[0] = hx; v0[1] = hx; v0[2] = lx; v0[3] = hy;
    v0[4] = hy; v0[5] = ly; v0[6] = hz; v0[7] = hz;
    v1[0] = lz; v1[1] = ONE; v1[2] = ONE; v1[3] = h2;
    v1[4] = l2; v1[5] = 0;  v1[6] = 0;  v1[7] = 0;
    *(short8*)&qry[tid * 16] = v0;
    *(short8*)&qry[tid * 16 + 8] = v1;
  }
  __syncthreads();

  // ---- One A-frag: wave w owns queries w*32 .. w*32+31 ----
  const short8 af = *(const short8*)&qry[(wave * 32 + n) * 16 + kg * 8];

  const float INF = 3.402823466e38f;
  float acc[16];
  #pragma unroll
  for (int r = 0; r < 16; ++r) acc[r] = INF;
  const float16v z = {};

  const float4* T4 = (const float4*)Tb;
  for (int ch = 0; ch < NCH; ++ch) {
    __syncthreads();
    // ---- Stage 1024 targets (4/thread: 3 float4 loads -> swizzled recs) ----
    {
      const int g = ch * (TCH / 4) + tid;
      const float4 a = T4[g * 3 + 0];
      const float4 c = T4[g * 3 + 1];
      const float4 d = T4[g * 3 + 2];
      const float X[4] = {a.x, a.w, c.z, d.y};
      const float Y[4] = {a.y, c.x, c.w, d.z};
      const float Z[4] = {a.z, c.y, d.x, d.w};
      #pragma unroll
      for (int p = 0; p < 4; ++p) {
        const float x = X[p], y = Y[p], zc = Z[p];
        const float t2 = fmaf(x, x, fmaf(y, y, zc * zc));
        const unsigned short hx = f2bf(x), hy = f2bf(y), hz = f2bf(zc);
        const unsigned short lx = f2bf(x - bf2f(hx)), ly = f2bf(y - bf2f(hy)),
                             lz = f2bf(zc - bf2f(hz));
        const unsigned short h2 = f2bf(t2), l2 = f2bf(t2 - bf2f(h2));
        const unsigned short ONE = 0x3F80;
        short8 v0, v1;
        v0[0] = hx; v0[1] = lx; v0[2] = hx; v0[3] = hy;
        v0[4] = ly; v0[5] = hy; v0[6] = hz; v0[7] = lz;
        v1[0] = hz; v1[1] = h2; v1[2] = l2; v1[3] = ONE;
        v1[4] = ONE; v1[5] = 0; v1[6] = 0; v1[7] = 0;
        const int j = tid * 4 + p;
        *(short8*)&tgt[toff(j, 0)] = v0;
        *(short8*)&tgt[toff(j, 1)] = v1;
      }
    }
    __syncthreads();

    // ---- Two-deep software-pipelined compute over 16 tile-pairs ----
    // reads 2 iters ahead, MFMA results consumed 1 iter later.
    short8 c0 = *(const short8*)&tgt[toff(0 * 64 + n, kg)];
    short8 c1 = *(const short8*)&tgt[toff(0 * 64 + 32 + n, kg)];
    short8 c2 = *(const short8*)&tgt[toff(1 * 64 + n, kg)];
    short8 c3 = *(const short8*)&tgt[toff(1 * 64 + 32 + n, kg)];
    float16v d0 = __builtin_amdgcn_mfma_f32_32x32x16_bf16(af, c0, z, 0, 0, 0);
    float16v d1 = __builtin_amdgcn_mfma_f32_32x32x16_bf16(af, c1, z, 0, 0, 0);
    c0 = c2;
    c1 = c3;
    #pragma unroll 2
    for (int tp = 1; tp < NTP; ++tp) {
      // MFMA for current pair from reads issued last iteration:
      const float16v e0 = __builtin_amdgcn_mfma_f32_32x32x16_bf16(af, c0, z, 0, 0, 0);
      const float16v e1 = __builtin_amdgcn_mfma_f32_32x32x16_bf16(af, c1, z, 0, 0, 0);
      // Issue reads for the next pair (clamped re-read on the last iter):
      const int tn = (tp + 1 < NTP) ? tp + 1 : tp;
      c0 = *(const short8*)&tgt[toff(tn * 64 + n, kg)];
      c1 = *(const short8*)&tgt[toff(tn * 64 + 32 + n, kg)];
      // Consume previous pair's results (produced a full iteration ago):
      #pragma unroll
      for (int r = 0; r < 16; ++r)
        acc[r] = fminf(fminf(d0[r], d1[r]), acc[r]);  // v_min3_f32
      d0 = e0;
      d1 = e1;
    }
    #pragma unroll
    for (int r = 0; r < 16; ++r)
      acc[r] = fminf(fminf(d0[r], d1[r]), acc[r]);
  }

  // ---- Min across the 32 cols within each kg half ----
  #pragma unroll
  for (int m = 1; m <= 16; m <<= 1) {
    #pragma unroll
    for (int r = 0; r < 16; ++r)
      acc[r] = fminf(acc[r], __shfl_xor(acc[r], m, 64));
  }

  // ---- Epilogue: lanes 0/32 hold disjoint row sets; sqrt+reduce+atomic ----
  float s = 0.0f;
  if (n == 0) {
    #pragma unroll
    for (int r = 0; r < 16; ++r)
      s += sqrtf(fmaxf(acc[r], 0.0f));
  }
  s += __shfl_xor(s, 32, 64);  // combine kg=0 / kg=1 partial sums
  if (lane == 0) redbuf[wave] = s;
  __syncthreads();
  if (tid == 0) {
    // out = 0.01 * mean over 16 batches of per-batch chamfer sums
    atomicAdd(out, (redbuf[0] + redbuf[1] + redbuf[2] + redbuf[3]) * (0.01f / 16.0f));
  }
}

extern "C" void kernel_launch(void* const* d_in, const int* in_sizes, int n_in,
                              void* d_out, int out_size, void* d_ws, size_t ws_size,
                              hipStream_t stream) {
  const float* shape = (const float*)d_in[0];
  const float* tmpl = (const float*)d_in[1];
  float* out = (float*)d_out;

  // d_out is poisoned to 0xAA before every timed launch; atomics need zeros.
  hipMemsetAsync(out, 0, sizeof(float) * out_size, stream);

  dim3 grid(NPTS / QPB, NBATCH, 2);
  chamfer_mfma<<<grid, dim3(THREADS), 0, stream>>>(shape, tmpl, out);
}